// Round 1
// baseline (2120.456 us; speedup 1.0000x reference)
//
#include <hip/hip_runtime.h>
#include <hip/hip_bf16.h>
#include <stdint.h>

#define S_LEN 4096
#define HN    32
#define SSD   64
#define KD    2048      // D_IN = H*SS = D_OUT
#define MROWS 16384     // B*S

typedef __attribute__((ext_vector_type(4))) float f32x4;
typedef __attribute__((ext_vector_type(8))) short bf16x8;
typedef __attribute__((address_space(3))) char as3char;
typedef __attribute__((address_space(1))) char as1char;

__device__ __forceinline__ unsigned short f2bf(float f){
  unsigned int u = __float_as_uint(f);
  u += 0x7FFFu + ((u >> 16) & 1u);   // round-to-nearest-even
  return (unsigned short)(u >> 16);
}

// ---------------- convert f32 -> bf16 (for W_out) ----------------
__global__ __launch_bounds__(256) void cvt_bf16_k(const float* __restrict__ src,
                                                  unsigned short* __restrict__ dst){
  int i = (blockIdx.x * 256 + threadIdx.x) * 4;
  float4 v = *(const float4*)(src + i);
  ushort4 r;
  r.x = f2bf(v.x); r.y = f2bf(v.y); r.z = f2bf(v.z); r.w = f2bf(v.w);
  *(ushort4*)(dst + i) = r;
}

// ---------------- GEMM1: hx = x * W_in^T + bias (f32 src, reg-staged cvt) ----------------
__global__ __launch_bounds__(256) void gemm1_k(const float* __restrict__ A,   // x [MROWS][KD]
                                               const float* __restrict__ Bw,  // W_in [2048][KD]
                                               const float* __restrict__ bias,// [2048]
                                               float* __restrict__ C){        // hx [MROWS][2048]
  __shared__ short As[128*32];
  __shared__ short Bs[128*32];
  const int tid  = threadIdx.x;
  const int bn   = blockIdx.x & 15;
  const int bm   = blockIdx.x >> 4;
  const int lane = tid & 63;
  const int wv   = tid >> 6;
  const int wm   = (wv >> 1) * 64;
  const int wn   = (wv & 1) * 64;
  const int srow = tid >> 1;
  const int scol = (tid & 1) * 16;
  const float* aSrc = A  + (size_t)(bm*128 + srow)*KD + scol;
  const float* bSrc = Bw + (size_t)(bn*128 + srow)*KD + scol;

  f32x4 acc[4][4];
#pragma unroll
  for (int i=0;i<4;i++)
#pragma unroll
    for (int j=0;j<4;j++)
#pragma unroll
      for (int q=0;q<4;q++) acc[i][j][q] = 0.0f;

  float aR[16], bR[16];
#pragma unroll
  for (int i=0;i<4;i++){
    ((float4*)aR)[i] = *(const float4*)(aSrc + 4*i);
    ((float4*)bR)[i] = *(const float4*)(bSrc + 4*i);
  }

  const int fr  = lane & 15;
  const int fko = (lane >> 4) * 8;

  for (int kt=0; kt<KD/32; ++kt){
    // convert current tile (registers)
    bf16x8 a0, a1, b0, b1;
#pragma unroll
    for (int i=0;i<8;i++){
      a0[i] = (short)f2bf(aR[i]);   a1[i] = (short)f2bf(aR[8+i]);
      b0[i] = (short)f2bf(bR[i]);   b1[i] = (short)f2bf(bR[8+i]);
    }
    __syncthreads();                 // previous tile's frag reads done
    short* ap = &As[srow*32 + scol];
    short* bp = &Bs[srow*32 + scol];
    *(bf16x8*)ap     = a0; *(bf16x8*)(ap+8) = a1;
    *(bf16x8*)bp     = b0; *(bf16x8*)(bp+8) = b1;
    __syncthreads();
    if (kt + 1 < KD/32){             // prefetch next tile; overlaps MFMA below
#pragma unroll
      for (int i=0;i<4;i++){
        ((float4*)aR)[i] = *(const float4*)(aSrc + (kt+1)*32 + 4*i);
        ((float4*)bR)[i] = *(const float4*)(bSrc + (kt+1)*32 + 4*i);
      }
    }
    bf16x8 af[4], bq[4];
#pragma unroll
    for (int mt=0; mt<4; mt++) af[mt] = *(const bf16x8*)&As[(wm + mt*16 + fr)*32 + fko];
#pragma unroll
    for (int nt=0; nt<4; nt++) bq[nt] = *(const bf16x8*)&Bs[(wn + nt*16 + fr)*32 + fko];
#pragma unroll
    for (int mt=0; mt<4; mt++)
#pragma unroll
      for (int nt=0; nt<4; nt++)
        acc[mt][nt] = __builtin_amdgcn_mfma_f32_16x16x32_bf16(af[mt], bq[nt], acc[mt][nt], 0, 0, 0);
  }

  float bv[4];
#pragma unroll
  for (int nt=0; nt<4; nt++) bv[nt] = bias[bn*128 + wn + nt*16 + fr];
#pragma unroll
  for (int mt=0; mt<4; mt++)
#pragma unroll
    for (int nt=0; nt<4; nt++){
      const int col = bn*128 + wn + nt*16 + fr;
#pragma unroll
      for (int q=0; q<4; q++){
        const int row = bm*128 + wm + mt*16 + (lane>>4)*4 + q;
        C[(size_t)row*KD + col] = acc[mt][nt][q] + bv[nt];
      }
    }
}

// ---------------- scan: y_t = tanh(W_h y_{t-1} + hx_t), one wave per (b,h) ----------------
__global__ __launch_bounds__(64) void scan_k(const float* __restrict__ hx,
                                             const float* __restrict__ sw,   // [32][64][64]
                                             const float* __restrict__ st0,  // [4][32][64]
                                             unsigned short* __restrict__ ybf){ // [MROWS][2048] bf16
  const int b = blockIdx.x >> 5, h = blockIdx.x & 31;
  const int lane = threadIdx.x;
  float w[64];
  const float* wr = sw + ((size_t)(h*64 + lane))*64;
#pragma unroll
  for (int i=0;i<16;i++) ((float4*)w)[i] = ((const float4*)wr)[i];

  __shared__ __align__(16) float yb[2][64];
  float y0 = st0[(b*32 + h)*64 + lane];
  yb[0][lane] = y0;
  const float* hxp = hx + (size_t)b*S_LEN*KD + h*64 + lane;
  const size_t yo  = (size_t)b*S_LEN*KD + h*64 + lane;

  float hpre[4];
#pragma unroll
  for (int i=0;i<4;i++) hpre[i] = hxp[(size_t)i*KD];
  __syncthreads();

  int cur = 0;
#pragma unroll 4
  for (int t=0; t<S_LEN; ++t){
    const float hxv = hpre[t & 3];
    const int tn = (t + 4 < S_LEN) ? (t + 4) : (S_LEN - 1);
    hpre[t & 3] = hxp[(size_t)tn*KD];

    float acc0=0.f, acc1=0.f, acc2=0.f, acc3=0.f;
    const float4* yv4 = (const float4*)yb[cur];
#pragma unroll
    for (int g=0; g<16; g++){
      float4 yv = yv4[g];            // uniform-address LDS broadcast
      acc0 = fmaf(w[4*g+0], yv.x, acc0);
      acc1 = fmaf(w[4*g+1], yv.y, acc1);
      acc2 = fmaf(w[4*g+2], yv.z, acc2);
      acc3 = fmaf(w[4*g+3], yv.w, acc3);
    }
    const float u = (acc0+acc1) + (acc2+acc3) + hxv;
    const float e = __expf(2.0f*u);
    const float yn = 1.0f - 2.0f*__builtin_amdgcn_rcpf(e + 1.0f);  // tanh(u)
    yb[cur^1][lane] = yn;
    ybf[yo + (size_t)t*KD] = f2bf(yn);
    __syncthreads();
    cur ^= 1;
  }
}

// ---------------- GEMM3: out = y * W_out^T (bf16 src, global_load_lds) ----------------
__global__ __launch_bounds__(256) void gemm3_k(const unsigned short* __restrict__ A,  // y bf16
                                               const unsigned short* __restrict__ Bw, // W_out bf16
                                               float* __restrict__ C){
  __shared__ short As[128*32];
  __shared__ short Bs[128*32];
  const int tid  = threadIdx.x;
  const int bn   = blockIdx.x & 15;
  const int bm   = blockIdx.x >> 4;
  const int lane = tid & 63;
  const int wv   = tid >> 6;
  const int wvU  = __builtin_amdgcn_readfirstlane(wv);
  const int wm   = (wv >> 1) * 64;
  const int wn   = (wv & 1) * 64;

  f32x4 acc[4][4];
#pragma unroll
  for (int i=0;i<4;i++)
#pragma unroll
    for (int j=0;j<4;j++)
#pragma unroll
      for (int q=0;q<4;q++) acc[i][j][q] = 0.0f;

  as3char* asB = (as3char*)As;
  as3char* bsB = (as3char*)Bs;
  as1char* aG  = (as1char*)A;
  as1char* bG  = (as1char*)Bw;

  const int fr  = lane & 15;
  const int fko = (lane >> 4) * 8;

  for (int kt=0; kt<KD/32; ++kt){
    __syncthreads();                 // previous tile's frag reads done
#pragma unroll
    for (int c=0;c<2;c++){
      const int off  = (wvU*2 + c)*1024 + lane*16;
      const int row  = off >> 6;
      const int colB = off & 63;
      __builtin_amdgcn_global_load_lds(
        (__attribute__((address_space(1))) void*)(aG + (size_t)(bm*128 + row)*4096 + (size_t)kt*64 + colB),
        (__attribute__((address_space(3))) void*)(asB + (wvU*2 + c)*1024),
        16, 0, 0);
      __builtin_amdgcn_global_load_lds(
        (__attribute__((address_space(1))) void*)(bG + (size_t)(bn*128 + row)*4096 + (size_t)kt*64 + colB),
        (__attribute__((address_space(3))) void*)(bsB + (wvU*2 + c)*1024),
        16, 0, 0);
    }
    __syncthreads();                 // loads landed (vmcnt drain at barrier)

    bf16x8 af[4], bq[4];
#pragma unroll
    for (int mt=0; mt<4; mt++) af[mt] = *(const bf16x8*)&As[(wm + mt*16 + fr)*32 + fko];
#pragma unroll
    for (int nt=0; nt<4; nt++) bq[nt] = *(const bf16x8*)&Bs[(wn + nt*16 + fr)*32 + fko];
#pragma unroll
    for (int mt=0; mt<4; mt++)
#pragma unroll
      for (int nt=0; nt<4; nt++)
        acc[mt][nt] = __builtin_amdgcn_mfma_f32_16x16x32_bf16(af[mt], bq[nt], acc[mt][nt], 0, 0, 0);
  }

#pragma unroll
  for (int mt=0; mt<4; mt++)
#pragma unroll
    for (int nt=0; nt<4; nt++){
      const int col = bn*128 + wn + nt*16 + fr;
#pragma unroll
      for (int q=0; q<4; q++){
        const int row = bm*128 + wm + mt*16 + (lane>>4)*4 + q;
        C[(size_t)row*KD + col] = acc[mt][nt][q];
      }
    }
}

extern "C" void kernel_launch(void* const* d_in, const int* in_sizes, int n_in,
                              void* d_out, int out_size, void* d_ws, size_t ws_size,
                              hipStream_t stream) {
  const float* x      = (const float*)d_in[0];
  const float* st0    = (const float*)d_in[1];
  const float* w_in   = (const float*)d_in[2];
  const float* w_st   = (const float*)d_in[3];
  const float* b_st   = (const float*)d_in[4];
  const float* w_out  = (const float*)d_in[5];
  float* out = (float*)d_out;

  // workspace: hx f32 (134MB) | y bf16 (67MB) | W_out bf16 (8MB) = 200 MiB
  const size_t HX_B = (size_t)MROWS * KD * 4;       // 134217728
  const size_t Y_B  = (size_t)MROWS * KD * 2;       // 67108864
  const size_t WO_B = (size_t)KD * KD * 2;          // 8388608
  if (ws_size < HX_B + Y_B + WO_B) return;          // fail loudly rather than corrupt
  char* ws = (char*)d_ws;
  float*          hx   = (float*)ws;
  unsigned short* ybf  = (unsigned short*)(ws + HX_B);
  unsigned short* wobf = (unsigned short*)(ws + HX_B + Y_B);

  cvt_bf16_k<<<dim3((KD*KD)/1024), dim3(256), 0, stream>>>(w_out, wobf);
  gemm1_k  <<<dim3((MROWS/128)*(KD/128)), dim3(256), 0, stream>>>(x, w_in, b_st, hx);
  scan_k   <<<dim3(128), dim3(64), 0, stream>>>(hx, w_st, st0, ybf);
  gemm3_k  <<<dim3((MROWS/128)*(KD/128)), dim3(256), 0, stream>>>(ybf, wobf, out);
}

// Round 3
// 2110.312 us; speedup vs baseline: 1.0048x; 1.0048x over previous
//
#include <hip/hip_runtime.h>
#include <hip/hip_bf16.h>
#include <stdint.h>

#define S_LEN 4096
#define HN    32
#define SSD   64
#define KD    2048      // D_IN = H*SS = D_OUT
#define MROWS 16384     // B*S

typedef __attribute__((ext_vector_type(4))) float f32x4;
typedef __attribute__((ext_vector_type(8))) short bf16x8;
typedef __attribute__((address_space(3))) char as3char;
typedef __attribute__((address_space(1))) char as1char;

__device__ __forceinline__ unsigned short f2bf(float f){
  unsigned int u = __float_as_uint(f);
  u += 0x7FFFu + ((u >> 16) & 1u);   // round-to-nearest-even
  return (unsigned short)(u >> 16);
}

// ---------------- convert f32 -> bf16 (for W_out) ----------------
__global__ __launch_bounds__(256) void cvt_bf16_k(const float* __restrict__ src,
                                                  unsigned short* __restrict__ dst){
  int i = (blockIdx.x * 256 + threadIdx.x) * 4;
  float4 v = *(const float4*)(src + i);
  ushort4 r;
  r.x = f2bf(v.x); r.y = f2bf(v.y); r.z = f2bf(v.z); r.w = f2bf(v.w);
  *(ushort4*)(dst + i) = r;
}

// ---------------- GEMM1: hx = x * W_in^T + bias (f32 src, reg-staged cvt) ----------------
__global__ __launch_bounds__(256) void gemm1_k(const float* __restrict__ A,   // x [MROWS][KD]
                                               const float* __restrict__ Bw,  // W_in [2048][KD]
                                               const float* __restrict__ bias,// [2048]
                                               float* __restrict__ C){        // hx [MROWS][2048]
  __shared__ short As[128*32];
  __shared__ short Bs[128*32];
  const int tid  = threadIdx.x;
  const int bn   = blockIdx.x & 15;
  const int bm   = blockIdx.x >> 4;
  const int lane = tid & 63;
  const int wv   = tid >> 6;
  const int wm   = (wv >> 1) * 64;
  const int wn   = (wv & 1) * 64;
  const int srow = tid >> 1;
  const int scol = (tid & 1) * 16;
  const float* aSrc = A  + (size_t)(bm*128 + srow)*KD + scol;
  const float* bSrc = Bw + (size_t)(bn*128 + srow)*KD + scol;

  f32x4 acc[4][4];
#pragma unroll
  for (int i=0;i<4;i++)
#pragma unroll
    for (int j=0;j<4;j++)
#pragma unroll
      for (int q=0;q<4;q++) acc[i][j][q] = 0.0f;

  float aR[16], bR[16];
#pragma unroll
  for (int i=0;i<4;i++){
    ((float4*)aR)[i] = *(const float4*)(aSrc + 4*i);
    ((float4*)bR)[i] = *(const float4*)(bSrc + 4*i);
  }

  const int fr  = lane & 15;
  const int fko = (lane >> 4) * 8;

  for (int kt=0; kt<KD/32; ++kt){
    // convert current tile (registers)
    bf16x8 a0, a1, b0, b1;
#pragma unroll
    for (int i=0;i<8;i++){
      a0[i] = (short)f2bf(aR[i]);   a1[i] = (short)f2bf(aR[8+i]);
      b0[i] = (short)f2bf(bR[i]);   b1[i] = (short)f2bf(bR[8+i]);
    }
    __syncthreads();                 // previous tile's frag reads done
    short* ap = &As[srow*32 + scol];
    short* bp = &Bs[srow*32 + scol];
    *(bf16x8*)ap     = a0; *(bf16x8*)(ap+8) = a1;
    *(bf16x8*)bp     = b0; *(bf16x8*)(bp+8) = b1;
    __syncthreads();
    if (kt + 1 < KD/32){             // prefetch next tile; overlaps MFMA below
#pragma unroll
      for (int i=0;i<4;i++){
        ((float4*)aR)[i] = *(const float4*)(aSrc + (kt+1)*32 + 4*i);
        ((float4*)bR)[i] = *(const float4*)(bSrc + (kt+1)*32 + 4*i);
      }
    }
    bf16x8 af[4], bq[4];
#pragma unroll
    for (int mt=0; mt<4; mt++) af[mt] = *(const bf16x8*)&As[(wm + mt*16 + fr)*32 + fko];
#pragma unroll
    for (int nt=0; nt<4; nt++) bq[nt] = *(const bf16x8*)&Bs[(wn + nt*16 + fr)*32 + fko];
#pragma unroll
    for (int mt=0; mt<4; mt++)
#pragma unroll
      for (int nt=0; nt<4; nt++)
        acc[mt][nt] = __builtin_amdgcn_mfma_f32_16x16x32_bf16(af[mt], bq[nt], acc[mt][nt], 0, 0, 0);
  }

  float bv[4];
#pragma unroll
  for (int nt=0; nt<4; nt++) bv[nt] = bias[bn*128 + wn + nt*16 + fr];
#pragma unroll
  for (int mt=0; mt<4; mt++)
#pragma unroll
    for (int nt=0; nt<4; nt++){
      const int col = bn*128 + wn + nt*16 + fr;
#pragma unroll
      for (int q=0; q<4; q++){
        const int row = bm*128 + wm + mt*16 + (lane>>4)*4 + q;
        C[(size_t)row*KD + col] = acc[mt][nt][q] + bv[nt];
      }
    }
}

// ---------------- scan: y_t = tanh(W_h y_{t-1} + hx_t), one wave per (b,h) ----------------
// Single wave per block -> NO __syncthreads in the loop (it would emit
// s_waitcnt vmcnt(0) and drain the hx prefetch every step). Intra-wave LDS
// RAW ordering on the double buffer is handled by compiler lgkmcnt waits.
__global__ __launch_bounds__(64) void scan_k(const float* __restrict__ hx,
                                             const float* __restrict__ sw,   // [32][64][64]
                                             const float* __restrict__ st0,  // [4][32][64]
                                             unsigned short* __restrict__ ybf){ // [MROWS][2048] bf16
  const int b = blockIdx.x >> 5, h = blockIdx.x & 31;
  const int lane = threadIdx.x;
  float w[64];
  const float* wr = sw + ((size_t)(h*64 + lane))*64;
#pragma unroll
  for (int i=0;i<16;i++) ((float4*)w)[i] = ((const float4*)wr)[i];

  __shared__ __align__(16) float yb[2][64];
  float y0 = st0[(b*32 + h)*64 + lane];
  yb[0][lane] = y0;
  const float* hxp = hx + (size_t)b*S_LEN*KD + h*64 + lane;
  const size_t yo  = (size_t)b*S_LEN*KD + h*64 + lane;

  float hpre[8];
#pragma unroll
  for (int i=0;i<8;i++) hpre[i] = hxp[(size_t)i*KD];

  int cur = 0;
#pragma unroll 8
  for (int t=0; t<S_LEN; ++t){
    const float hxv = hpre[t & 7];
    const int tn = (t + 8 < S_LEN) ? (t + 8) : (S_LEN - 1);
    hpre[t & 7] = hxp[(size_t)tn*KD];

    float acc0=0.f, acc1=0.f, acc2=0.f, acc3=0.f;
    const float4* yv4 = (const float4*)yb[cur];
#pragma unroll
    for (int g=0; g<16; g++){
      float4 yv = yv4[g];            // uniform-address LDS broadcast
      acc0 = fmaf(w[4*g+0], yv.x, acc0);
      acc1 = fmaf(w[4*g+1], yv.y, acc1);
      acc2 = fmaf(w[4*g+2], yv.z, acc2);
      acc3 = fmaf(w[4*g+3], yv.w, acc3);
    }
    const float u = (acc0+acc1) + (acc2+acc3) + hxv;
    const float e = __expf(2.0f*u);
    const float yn = 1.0f - 2.0f*__builtin_amdgcn_rcpf(e + 1.0f);  // tanh(u)
    yb[cur^1][lane] = yn;
    ybf[yo + (size_t)t*KD] = f2bf(yn);
    cur ^= 1;
  }
}

// ---------------- GEMM3: out = y * W_out^T (bf16 src, global_load_lds) ----------------
__global__ __launch_bounds__(256) void gemm3_k(const unsigned short* __restrict__ A,  // y bf16
                                               const unsigned short* __restrict__ Bw, // W_out bf16
                                               float* __restrict__ C){
  __shared__ short As[128*32];
  __shared__ short Bs[128*32];
  const int tid  = threadIdx.x;
  const int bn   = blockIdx.x & 15;
  const int bm   = blockIdx.x >> 4;
  const int lane = tid & 63;
  const int wv   = tid >> 6;
  const int wvU  = __builtin_amdgcn_readfirstlane(wv);
  const int wm   = (wv >> 1) * 64;
  const int wn   = (wv & 1) * 64;

  f32x4 acc[4][4];
#pragma unroll
  for (int i=0;i<4;i++)
#pragma unroll
    for (int j=0;j<4;j++)
#pragma unroll
      for (int q=0;q<4;q++) acc[i][j][q] = 0.0f;

  as3char* asB = (as3char*)As;
  as3char* bsB = (as3char*)Bs;
  as1char* aG  = (as1char*)A;
  as1char* bG  = (as1char*)Bw;

  const int fr  = lane & 15;
  const int fko = (lane >> 4) * 8;

  for (int kt=0; kt<KD/32; ++kt){
    __syncthreads();                 // previous tile's frag reads done
#pragma unroll
    for (int c=0;c<2;c++){
      const int off  = (wvU*2 + c)*1024 + lane*16;
      const int row  = off >> 6;
      const int colB = off & 63;
      __builtin_amdgcn_global_load_lds(
        (__attribute__((address_space(1))) void*)(aG + (size_t)(bm*128 + row)*4096 + (size_t)kt*64 + colB),
        (__attribute__((address_space(3))) void*)(asB + (wvU*2 + c)*1024),
        16, 0, 0);
      __builtin_amdgcn_global_load_lds(
        (__attribute__((address_space(1))) void*)(bG + (size_t)(bn*128 + row)*4096 + (size_t)kt*64 + colB),
        (__attribute__((address_space(3))) void*)(bsB + (wvU*2 + c)*1024),
        16, 0, 0);
    }
    __syncthreads();                 // loads landed (vmcnt drain at barrier)

    bf16x8 af[4], bq[4];
#pragma unroll
    for (int mt=0; mt<4; mt++) af[mt] = *(const bf16x8*)&As[(wm + mt*16 + fr)*32 + fko];
#pragma unroll
    for (int nt=0; nt<4; nt++) bq[nt] = *(const bf16x8*)&Bs[(wn + nt*16 + fr)*32 + fko];
#pragma unroll
    for (int mt=0; mt<4; mt++)
#pragma unroll
      for (int nt=0; nt<4; nt++)
        acc[mt][nt] = __builtin_amdgcn_mfma_f32_16x16x32_bf16(af[mt], bq[nt], acc[mt][nt], 0, 0, 0);
  }

#pragma unroll
  for (int mt=0; mt<4; mt++)
#pragma unroll
    for (int nt=0; nt<4; nt++){
      const int col = bn*128 + wn + nt*16 + fr;
#pragma unroll
      for (int q=0; q<4; q++){
        const int row = bm*128 + wm + mt*16 + (lane>>4)*4 + q;
        C[(size_t)row*KD + col] = acc[mt][nt][q];
      }
    }
}

extern "C" void kernel_launch(void* const* d_in, const int* in_sizes, int n_in,
                              void* d_out, int out_size, void* d_ws, size_t ws_size,
                              hipStream_t stream) {
  const float* x      = (const float*)d_in[0];
  const float* st0    = (const float*)d_in[1];
  const float* w_in   = (const float*)d_in[2];
  const float* w_st   = (const float*)d_in[3];
  const float* b_st   = (const float*)d_in[4];
  const float* w_out  = (const float*)d_in[5];
  float* out = (float*)d_out;

  // workspace: hx f32 (134MB) | y bf16 (67MB) | W_out bf16 (8MB) = 200 MiB
  const size_t HX_B = (size_t)MROWS * KD * 4;       // 134217728
  const size_t Y_B  = (size_t)MROWS * KD * 2;       // 67108864
  const size_t WO_B = (size_t)KD * KD * 2;          // 8388608
  if (ws_size < HX_B + Y_B + WO_B) return;          // fail loudly rather than corrupt
  char* ws = (char*)d_ws;
  float*          hx   = (float*)ws;
  unsigned short* ybf  = (unsigned short*)(ws + HX_B);
  unsigned short* wobf = (unsigned short*)(ws + HX_B + Y_B);

  cvt_bf16_k<<<dim3((KD*KD)/1024), dim3(256), 0, stream>>>(w_out, wobf);
  gemm1_k  <<<dim3((MROWS/128)*(KD/128)), dim3(256), 0, stream>>>(x, w_in, b_st, hx);
  scan_k   <<<dim3(128), dim3(64), 0, stream>>>(hx, w_st, st0, ybf);
  gemm3_k  <<<dim3((MROWS/128)*(KD/128)), dim3(256), 0, stream>>>(ybf, wobf, out);
}

// Round 4
// 1656.183 us; speedup vs baseline: 1.2803x; 1.2742x over previous
//
#include <hip/hip_runtime.h>
#include <hip/hip_bf16.h>
#include <stdint.h>

#define S_LEN 4096
#define HN    32
#define SSD   64
#define KD    2048      // D_IN = H*SS = D_OUT
#define MROWS 16384     // B*S

typedef __attribute__((ext_vector_type(4))) float f32x4;
typedef __attribute__((ext_vector_type(8))) short bf16x8;
typedef __attribute__((address_space(3))) char as3char;
typedef __attribute__((address_space(1))) char as1char;

__device__ __forceinline__ unsigned short f2bf(float f){
  unsigned int u = __float_as_uint(f);
  u += 0x7FFFu + ((u >> 16) & 1u);   // round-to-nearest-even
  return (unsigned short)(u >> 16);
}

// ---------------- convert f32 -> bf16 (for W_out) ----------------
__global__ __launch_bounds__(256) void cvt_bf16_k(const float* __restrict__ src,
                                                  unsigned short* __restrict__ dst){
  int i = (blockIdx.x * 256 + threadIdx.x) * 4;
  float4 v = *(const float4*)(src + i);
  ushort4 r;
  r.x = f2bf(v.x); r.y = f2bf(v.y); r.z = f2bf(v.z); r.w = f2bf(v.w);
  *(ushort4*)(dst + i) = r;
}

// ---------------- GEMM1: hx = x * W_in^T + bias (f32 src, reg-staged cvt) ----------------
__global__ __launch_bounds__(256) void gemm1_k(const float* __restrict__ A,   // x [MROWS][KD]
                                               const float* __restrict__ Bw,  // W_in [2048][KD]
                                               const float* __restrict__ bias,// [2048]
                                               float* __restrict__ C){        // hx [MROWS][2048]
  __shared__ short As[128*32];
  __shared__ short Bs[128*32];
  const int tid  = threadIdx.x;
  const int bn   = blockIdx.x & 15;
  const int bm   = blockIdx.x >> 4;
  const int lane = tid & 63;
  const int wv   = tid >> 6;
  const int wm   = (wv >> 1) * 64;
  const int wn   = (wv & 1) * 64;
  const int srow = tid >> 1;
  const int scol = (tid & 1) * 16;
  const float* aSrc = A  + (size_t)(bm*128 + srow)*KD + scol;
  const float* bSrc = Bw + (size_t)(bn*128 + srow)*KD + scol;

  f32x4 acc[4][4];
#pragma unroll
  for (int i=0;i<4;i++)
#pragma unroll
    for (int j=0;j<4;j++)
#pragma unroll
      for (int q=0;q<4;q++) acc[i][j][q] = 0.0f;

  float aR[16], bR[16];
#pragma unroll
  for (int i=0;i<4;i++){
    ((float4*)aR)[i] = *(const float4*)(aSrc + 4*i);
    ((float4*)bR)[i] = *(const float4*)(bSrc + 4*i);
  }

  const int fr  = lane & 15;
  const int fko = (lane >> 4) * 8;

  for (int kt=0; kt<KD/32; ++kt){
    // convert current tile (registers)
    bf16x8 a0, a1, b0, b1;
#pragma unroll
    for (int i=0;i<8;i++){
      a0[i] = (short)f2bf(aR[i]);   a1[i] = (short)f2bf(aR[8+i]);
      b0[i] = (short)f2bf(bR[i]);   b1[i] = (short)f2bf(bR[8+i]);
    }
    __syncthreads();                 // previous tile's frag reads done
    short* ap = &As[srow*32 + scol];
    short* bp = &Bs[srow*32 + scol];
    *(bf16x8*)ap     = a0; *(bf16x8*)(ap+8) = a1;
    *(bf16x8*)bp     = b0; *(bf16x8*)(bp+8) = b1;
    __syncthreads();
    if (kt + 1 < KD/32){             // prefetch next tile; overlaps MFMA below
#pragma unroll
      for (int i=0;i<4;i++){
        ((float4*)aR)[i] = *(const float4*)(aSrc + (kt+1)*32 + 4*i);
        ((float4*)bR)[i] = *(const float4*)(bSrc + (kt+1)*32 + 4*i);
      }
    }
    bf16x8 af[4], bq[4];
#pragma unroll
    for (int mt=0; mt<4; mt++) af[mt] = *(const bf16x8*)&As[(wm + mt*16 + fr)*32 + fko];
#pragma unroll
    for (int nt=0; nt<4; nt++) bq[nt] = *(const bf16x8*)&Bs[(wn + nt*16 + fr)*32 + fko];
#pragma unroll
    for (int mt=0; mt<4; mt++)
#pragma unroll
      for (int nt=0; nt<4; nt++)
        acc[mt][nt] = __builtin_amdgcn_mfma_f32_16x16x32_bf16(af[mt], bq[nt], acc[mt][nt], 0, 0, 0);
  }

  float bv[4];
#pragma unroll
  for (int nt=0; nt<4; nt++) bv[nt] = bias[bn*128 + wn + nt*16 + fr];
#pragma unroll
  for (int mt=0; mt<4; mt++)
#pragma unroll
    for (int nt=0; nt<4; nt++){
      const int col = bn*128 + wn + nt*16 + fr;
#pragma unroll
      for (int q=0; q<4; q++){
        const int row = bm*128 + wm + mt*16 + (lane>>4)*4 + q;
        C[(size_t)row*KD + col] = acc[mt][nt][q] + bv[nt];
      }
    }
}

// ---------------- scan: y_t = tanh(W_h y_{t-1} + hx_t) ----------------
// One (b,h) chain per block of 256 threads (4 waves). Output o = 16*wave + (lane&15)
// is computed by 4 lanes (p = lane>>4), each doing 16 FMAs over its quarter of y,
// reduced with shfl_xor(16)+shfl_xor(32). Cross-wave y exchange via LDS double
// buffer with ONE raw barrier per step: s_waitcnt lgkmcnt(0) + s_barrier —
// LDS-only wait keeps the 8-deep hx prefetch and ybf stores in flight (a plain
// __syncthreads would drain vmcnt(0) every step).
__global__ __launch_bounds__(256) void scan_k(const float* __restrict__ hx,
                                              const float* __restrict__ sw,   // [32][64][64]
                                              const float* __restrict__ st0,  // [4][32][64]
                                              unsigned short* __restrict__ ybf){ // [MROWS][2048] bf16
  const int b   = blockIdx.x >> 5, h = blockIdx.x & 31;
  const int tid = threadIdx.x;
  const int w4  = tid >> 6;           // wave 0..3
  const int lane= tid & 63;
  const int q16 = lane & 15;          // output-within-wave
  const int p   = lane >> 4;          // quarter 0..3
  const int o   = w4*16 + q16;        // output index 0..63

  // W[o][16p + j], j = 0..15
  float w[16];
  const float* wr = sw + ((size_t)(h*64 + o))*64 + p*16;
#pragma unroll
  for (int i=0;i<4;i++) ((float4*)w)[i] = ((const float4*)wr)[i];

  __shared__ __align__(16) float yb[2][64];
  if (tid < 64) yb[0][tid] = st0[(b*32 + h)*64 + tid];
  __syncthreads();                    // prologue only

  const float* hxp = hx + (size_t)b*S_LEN*KD + h*64 + o;
  const size_t yo  = (size_t)b*S_LEN*KD + h*64 + o;   // used by p==0 lanes

  float hpre[8];
#pragma unroll
  for (int i=0;i<8;i++) hpre[i] = hxp[(size_t)i*KD];

  int cur = 0;
#pragma unroll 8
  for (int t=0; t<S_LEN; ++t){
    const float hxv = hpre[t & 7];
    const int tn = (t + 8 < S_LEN) ? (t + 8) : (S_LEN - 1);
    hpre[t & 7] = hxp[(size_t)tn*KD];

    const float4* yv4 = (const float4*)&yb[cur][p*16];
    float4 y0v = yv4[0], y1v = yv4[1], y2v = yv4[2], y3v = yv4[3];
    float a0 = 0.f, a1 = 0.f, a2 = 0.f, a3 = 0.f;
    a0 = fmaf(w[ 0], y0v.x, a0); a1 = fmaf(w[ 1], y0v.y, a1);
    a2 = fmaf(w[ 2], y0v.z, a2); a3 = fmaf(w[ 3], y0v.w, a3);
    a0 = fmaf(w[ 4], y1v.x, a0); a1 = fmaf(w[ 5], y1v.y, a1);
    a2 = fmaf(w[ 6], y1v.z, a2); a3 = fmaf(w[ 7], y1v.w, a3);
    a0 = fmaf(w[ 8], y2v.x, a0); a1 = fmaf(w[ 9], y2v.y, a1);
    a2 = fmaf(w[10], y2v.z, a2); a3 = fmaf(w[11], y2v.w, a3);
    a0 = fmaf(w[12], y3v.x, a0); a1 = fmaf(w[13], y3v.y, a1);
    a2 = fmaf(w[14], y3v.z, a2); a3 = fmaf(w[15], y3v.w, a3);
    float s = (a0 + a1) + (a2 + a3);
    s += __shfl_xor(s, 16, 64);       // sum quarters p ^ 1 (of pairs 0/1, 2/3)
    s += __shfl_xor(s, 32, 64);       // sum across halves
    const float u  = s + hxv;
    const float e  = __expf(2.0f*u);
    const float yn = 1.0f - 2.0f*__builtin_amdgcn_rcpf(e + 1.0f);  // tanh(u)
    if (p == 0){
      yb[cur^1][o] = yn;
      ybf[yo + (size_t)t*KD] = f2bf(yn);
    }
    // LDS-only drain + barrier: hx prefetch / ybf stores stay in flight.
    asm volatile("s_waitcnt lgkmcnt(0)\n\ts_barrier" ::: "memory");
    cur ^= 1;
  }
}

// ---------------- GEMM3: out = y * W_out^T (bf16 src, global_load_lds) ----------------
__global__ __launch_bounds__(256) void gemm3_k(const unsigned short* __restrict__ A,  // y bf16
                                               const unsigned short* __restrict__ Bw, // W_out bf16
                                               float* __restrict__ C){
  __shared__ short As[128*32];
  __shared__ short Bs[128*32];
  const int tid  = threadIdx.x;
  const int bn   = blockIdx.x & 15;
  const int bm   = blockIdx.x >> 4;
  const int lane = tid & 63;
  const int wv   = tid >> 6;
  const int wvU  = __builtin_amdgcn_readfirstlane(wv);
  const int wm   = (wv >> 1) * 64;
  const int wn   = (wv & 1) * 64;

  f32x4 acc[4][4];
#pragma unroll
  for (int i=0;i<4;i++)
#pragma unroll
    for (int j=0;j<4;j++)
#pragma unroll
      for (int q=0;q<4;q++) acc[i][j][q] = 0.0f;

  as3char* asB = (as3char*)As;
  as3char* bsB = (as3char*)Bs;
  as1char* aG  = (as1char*)A;
  as1char* bG  = (as1char*)Bw;

  const int fr  = lane & 15;
  const int fko = (lane >> 4) * 8;

  for (int kt=0; kt<KD/32; ++kt){
    __syncthreads();                 // previous tile's frag reads done
#pragma unroll
    for (int c=0;c<2;c++){
      const int off  = (wvU*2 + c)*1024 + lane*16;
      const int row  = off >> 6;
      const int colB = off & 63;
      __builtin_amdgcn_global_load_lds(
        (__attribute__((address_space(1))) void*)(aG + (size_t)(bm*128 + row)*4096 + (size_t)kt*64 + colB),
        (__attribute__((address_space(3))) void*)(asB + (wvU*2 + c)*1024),
        16, 0, 0);
      __builtin_amdgcn_global_load_lds(
        (__attribute__((address_space(1))) void*)(bG + (size_t)(bn*128 + row)*4096 + (size_t)kt*64 + colB),
        (__attribute__((address_space(3))) void*)(bsB + (wvU*2 + c)*1024),
        16, 0, 0);
    }
    __syncthreads();                 // loads landed (vmcnt drain at barrier)

    bf16x8 af[4], bq[4];
#pragma unroll
    for (int mt=0; mt<4; mt++) af[mt] = *(const bf16x8*)&As[(wm + mt*16 + fr)*32 + fko];
#pragma unroll
    for (int nt=0; nt<4; nt++) bq[nt] = *(const bf16x8*)&Bs[(wn + nt*16 + fr)*32 + fko];
#pragma unroll
    for (int mt=0; mt<4; mt++)
#pragma unroll
      for (int nt=0; nt<4; nt++)
        acc[mt][nt] = __builtin_amdgcn_mfma_f32_16x16x32_bf16(af[mt], bq[nt], acc[mt][nt], 0, 0, 0);
  }

#pragma unroll
  for (int mt=0; mt<4; mt++)
#pragma unroll
    for (int nt=0; nt<4; nt++){
      const int col = bn*128 + wn + nt*16 + fr;
#pragma unroll
      for (int q=0; q<4; q++){
        const int row = bm*128 + wm + mt*16 + (lane>>4)*4 + q;
        C[(size_t)row*KD + col] = acc[mt][nt][q];
      }
    }
}

extern "C" void kernel_launch(void* const* d_in, const int* in_sizes, int n_in,
                              void* d_out, int out_size, void* d_ws, size_t ws_size,
                              hipStream_t stream) {
  const float* x      = (const float*)d_in[0];
  const float* st0    = (const float*)d_in[1];
  const float* w_in   = (const float*)d_in[2];
  const float* w_st   = (const float*)d_in[3];
  const float* b_st   = (const float*)d_in[4];
  const float* w_out  = (const float*)d_in[5];
  float* out = (float*)d_out;

  // workspace: hx f32 (134MB) | y bf16 (67MB) | W_out bf16 (8MB) = 200 MiB
  const size_t HX_B = (size_t)MROWS * KD * 4;       // 134217728
  const size_t Y_B  = (size_t)MROWS * KD * 2;       // 67108864
  const size_t WO_B = (size_t)KD * KD * 2;          // 8388608
  if (ws_size < HX_B + Y_B + WO_B) return;          // fail loudly rather than corrupt
  char* ws = (char*)d_ws;
  float*          hx   = (float*)ws;
  unsigned short* ybf  = (unsigned short*)(ws + HX_B);
  unsigned short* wobf = (unsigned short*)(ws + HX_B + Y_B);

  cvt_bf16_k<<<dim3((KD*KD)/1024), dim3(256), 0, stream>>>(w_out, wobf);
  gemm1_k  <<<dim3((MROWS/128)*(KD/128)), dim3(256), 0, stream>>>(x, w_in, b_st, hx);
  scan_k   <<<dim3(128), dim3(256), 0, stream>>>(hx, w_st, st0, ybf);
  gemm3_k  <<<dim3((MROWS/128)*(KD/128)), dim3(256), 0, stream>>>(ybf, wobf, out);
}